// Round 4
// baseline (84166.901 us; speedup 1.0000x reference)
//
#include <hip/hip_runtime.h>

// ---------------- problem constants ----------------
#define BB   64
#define TT   512
#define NVOC 16
#define KIN  256
#define HH   512
#define GG   2048
#define FF   64

#define NWG  256
#define NTHR 512

// LDS layout (float offsets); weight rows padded to 524 floats.
#define U1W_OFF  0
#define W2W_OFF  8384        // 16*524
#define U2W_OFF  16768
#define HLDS_OFF 25152       // [32][256] float, XOR-swizzled at float4 granularity
#define ZRED_OFF 33344       // [8][32][17]
#define TABW_OFF 37696       // [16][16]
#define B2W_OFF  37952       // [16]
#define LDS_FLOATS 37968
#define LDS_BYTES  (LDS_FLOATS * 4)

// ws layout: 32 KB flag region, then floats: h1 ping/pong, h2 ping/pong.
// Flags: A-flags half bh at words [bh*2048 .. ), B-flags at 4096 + bh*2048.
// Each flag on its own 64B line (stride 16 words). Monotonic step-stamps,
// never reset (no reset race); zeroed host-side per launch.
#define FLAG_WORDS 8192      // 32 KB
#define H1A_OFF 0
#define H1B_OFF 32768
#define H2A_OFF 65536
#define H2B_OFF 98304

// arrive: WG-wide sync, then one release store (flushes this XCD's dirty L2
// so our h-writes reach the coherent point before the stamp is visible).
__device__ __forceinline__ void bar_arrive(unsigned* flag, unsigned val) {
  __syncthreads();
  if (threadIdx.x == 0)
    __hip_atomic_store(flag, val, __ATOMIC_RELEASE, __HIP_MEMORY_SCOPE_AGENT);
}

// wait: threads 0..127 poll the 128 per-WG flags in parallel (distinct 64B
// lines -> no hot-line serialization). Acquire per poll keeps R1/R3's proven
// cross-XCD visibility semantics; with split arrive/wait the expected poll
// count is ~1, so the per-poll invalidate is paid ~twice per step.
__device__ __forceinline__ void bar_wait(unsigned* flags, unsigned target) {
  if (threadIdx.x < 128) {
    unsigned* f = flags + threadIdx.x * 16;
    while (__hip_atomic_load(f, __ATOMIC_ACQUIRE, __HIP_MEMORY_SCOPE_AGENT) < target)
      __builtin_amdgcn_s_sleep(4);
  }
  __syncthreads();
}

// ---- h-chunk staging: global [32][512] slice -> LDS [32][256] swizzled ----
__device__ __forceinline__ void stage_ld(float4 v[4], const float* __restrict__ src, int tid) {
  #pragma unroll
  for (int jj = 0; jj < 4; ++jj) {
    int f4 = jj * 512 + tid;
    int b = f4 >> 6, k4l = f4 & 63;
    v[jj] = *reinterpret_cast<const float4*>(src + b * HH + k4l * 4);
  }
}
__device__ __forceinline__ void stage_st(float* __restrict__ hlds, const float4 v[4], int tid) {
  float4* h4 = reinterpret_cast<float4*>(hlds);
  #pragma unroll
  for (int jj = 0; jj < 4; ++jj) {
    int f4 = jj * 512 + tid;
    int b = f4 >> 6, k4l = f4 & 63;
    h4[b * 64 + (k4l ^ (b >> 3))] = v[jj];   // slot-XOR by row-group: reads conflict-free
  }
}

// ---- inner: 8 j-iters, each 1 w4 + 8 h4 ds_read_b128 + 32 FMA ----
__device__ __forceinline__ void inner8(float acc[8], const float* __restrict__ wrow,
                                       const float4* __restrict__ h4base, int kq8, int bg) {
  #pragma unroll
  for (int j = 0; j < 8; ++j) {
    int k4 = kq8 + j;
    float4 w = *reinterpret_cast<const float4*>(wrow + k4 * 4);
    const float4* hb = h4base + (k4 ^ bg);
    float4 h0 = hb[0 * 64], h1 = hb[1 * 64], h2 = hb[2 * 64], h3 = hb[3 * 64];
    float4 h4v = hb[4 * 64], h5 = hb[5 * 64], h6 = hb[6 * 64], h7 = hb[7 * 64];
    acc[0] += h0.x * w.x; acc[0] += h0.y * w.y; acc[0] += h0.z * w.z; acc[0] += h0.w * w.w;
    acc[1] += h1.x * w.x; acc[1] += h1.y * w.y; acc[1] += h1.z * w.z; acc[1] += h1.w * w.w;
    acc[2] += h2.x * w.x; acc[2] += h2.y * w.y; acc[2] += h2.z * w.z; acc[2] += h2.w * w.w;
    acc[3] += h3.x * w.x; acc[3] += h3.y * w.y; acc[3] += h3.z * w.z; acc[3] += h3.w * w.w;
    acc[4] += h4v.x * w.x; acc[4] += h4v.y * w.y; acc[4] += h4v.z * w.z; acc[4] += h4v.w * w.w;
    acc[5] += h5.x * w.x; acc[5] += h5.y * w.y; acc[5] += h5.z * w.z; acc[5] += h5.w * w.w;
    acc[6] += h6.x * w.x; acc[6] += h6.y * w.y; acc[6] += h6.z * w.z; acc[6] += h6.w * w.w;
    acc[7] += h7.x * w.x; acc[7] += h7.y * w.y; acc[7] += h7.z * w.z; acc[7] += h7.w * w.w;
  }
}

extern "C" __global__ void __launch_bounds__(NTHR, 2)
lstm_fused3(const int* __restrict__ tokens, const float* __restrict__ emb,
            const float* __restrict__ W1, const float* __restrict__ U1,
            const float* __restrict__ b1, const float* __restrict__ W2,
            const float* __restrict__ U2, const float* __restrict__ b2,
            const float* __restrict__ Wd, const float* __restrict__ bd,
            float* __restrict__ out, float* __restrict__ wsf,
            unsigned* __restrict__ flags)
{
  extern __shared__ float lds[];
  float* u1w  = lds + U1W_OFF;
  float* w2w  = lds + W2W_OFF;
  float* u2w  = lds + U2W_OFF;
  float* hlds = lds + HLDS_OFF;
  float* zred = lds + ZRED_OFF;
  float* tabw = lds + TABW_OFF;
  float* b2w  = lds + B2W_OFF;

  const int wg  = blockIdx.x;
  const int tid = threadIdx.x;
  const int bh  = wg >> 7;        // batch half (0/1): rows bh*32..+31
  const int ct  = wg & 127;       // col tile: hidden cols ct*4..+3
  const int hc0 = ct * 4;
  const int zcl = tid & 15;       // gate g=zcl>>2, col c=zcl&3
  const int bg  = (tid >> 4) & 3; // 8-row batch group
  const int kq  = tid >> 6;       // wave id = K-split (8-way)
  const int kq8 = kq * 8;

  unsigned* fA = flags + bh * 2048;          // this half's A flags
  unsigned* fB = flags + 4096 + bh * 2048;   // this half's B flags
  unsigned* myA = fA + ct * 16;
  unsigned* myB = fB + ct * 16;

  float* h1A = wsf + H1A_OFF; float* h1B = wsf + H1B_OFF;
  float* h2A = wsf + H2A_OFF; float* h2B = wsf + H2B_OFF;

  // ---------------- phase 0 ----------------
  { // weight slices -> LDS, transposed to [zc][k] rows of 524
    int k = tid;
    #pragma unroll
    for (int g = 0; g < 4; ++g) {
      float4 a = *reinterpret_cast<const float4*>(U1 + (size_t)k * GG + hc0 + 512 * g);
      u1w[(g * 4 + 0) * 524 + k] = a.x; u1w[(g * 4 + 1) * 524 + k] = a.y;
      u1w[(g * 4 + 2) * 524 + k] = a.z; u1w[(g * 4 + 3) * 524 + k] = a.w;
      float4 b_ = *reinterpret_cast<const float4*>(W2 + (size_t)k * GG + hc0 + 512 * g);
      w2w[(g * 4 + 0) * 524 + k] = b_.x; w2w[(g * 4 + 1) * 524 + k] = b_.y;
      w2w[(g * 4 + 2) * 524 + k] = b_.z; w2w[(g * 4 + 3) * 524 + k] = b_.w;
      float4 c_ = *reinterpret_cast<const float4*>(U2 + (size_t)k * GG + hc0 + 512 * g);
      u2w[(g * 4 + 0) * 524 + k] = c_.x; u2w[(g * 4 + 1) * 524 + k] = c_.y;
      u2w[(g * 4 + 2) * 524 + k] = c_.z; u2w[(g * 4 + 3) * 524 + k] = c_.w;
    }
  }
  if (tid < 256) { // token->z1 table for this WG's 16 z-cols (vocab=16)
    int v = tid >> 4, zz = tid & 15;
    int col = hc0 + (zz & 3) + ((zz >> 2) << 9);
    float a = b1[col];
    #pragma unroll 4
    for (int k = 0; k < KIN; ++k) a += emb[v * KIN + k] * W1[(size_t)k * GG + col];
    tabw[v * 16 + zz] = a;
  }
  if (tid < 16) b2w[tid] = b2[hc0 + (tid & 3) + ((tid >> 2) << 9)];
  { // zero t=0 read buffers (own half's slice)
    if (tid < 128)       h1A[bh * 16384 + ct * 128 + tid] = 0.f;
    else if (tid < 256)  h2A[bh * 16384 + ct * 128 + (tid - 128)] = 0.f;
  }
  bar_arrive(myA, 1u);           // release: flushes h zeros + nothing else dirty
  bar_arrive(myB, 1u);
  bar_wait(fA, 1u);              // all init writes of this half visible

  // persistent per-thread state (tid<128 owners): thread = (b = tid>>2, c = tid&3)
  float c1 = 0.f, hp1 = 0.f, c2 = 0.f, hp2 = 0.f;
  const int fb = tid >> 2;
  const int fc = tid & 3;

  const float4* h4base = reinterpret_cast<const float4*>(hlds) + bg * 512;
  const float* u1row = u1w + zcl * 524;
  const float* w2row = w2w + zcl * 524;
  const float* u2row = u2w + zcl * 524;

  for (int t = 0; t < TT; ++t) {
    float* h1r = (t & 1) ? h1B : h1A;
    float* h1w = (t & 1) ? h1A : h1B;
    float* h2r = (t & 1) ? h2B : h2A;
    float* h2w = (t & 1) ? h2A : h2B;
    const float* h1r_half = h1r + bh * 32 * HH;
    const float* h2r_half = h2r + bh * 32 * HH;
    const float* h1w_half = h1w + bh * 32 * HH;
    const unsigned stamp = (unsigned)t + 2u;

    float acc[8] = {0,0,0,0,0,0,0,0};
    float4 pre[4];

    // ---------- layer 1: z1 = tab1[tok] + h1r @ U1  (guarded by waitA(t-1)) ----------
    stage_ld(pre, h1r_half, tid);
    __syncthreads(); stage_st(hlds, pre, tid); __syncthreads();
    stage_ld(pre, h1r_half + 256, tid);           // chunk 1 under compute
    inner8(acc, u1row, h4base, kq8, bg);
    __syncthreads(); stage_st(hlds, pre, tid); __syncthreads();
    inner8(acc, u1row + 256, h4base, kq8, bg);

    __syncthreads();
    #pragma unroll
    for (int i = 0; i < 8; ++i) zred[kq * 544 + (bg * 8 + i) * 17 + zcl] = acc[i];
    __syncthreads();
    if (tid < 128) {
      float z[4];
      #pragma unroll
      for (int g = 0; g < 4; ++g) {
        float s = 0.f;
        #pragma unroll
        for (int q = 0; q < 8; ++q) s += zred[q * 544 + fb * 17 + g * 4 + fc];
        z[g] = s;
      }
      int tok = tokens[(bh * 32 + fb) * TT + t];
      #pragma unroll
      for (int g = 0; g < 4; ++g) z[g] += tabw[tok * 16 + g * 4 + fc];
      float si = 1.f / (1.f + expf(-z[0]));
      float sf = 1.f / (1.f + expf(-z[1]));
      float gg = tanhf(z[2]);
      float so = 1.f / (1.f + expf(-z[3]));
      float cn = sf * c1 + si * gg;
      float hn = so * tanhf(cn);
      if (tok == 0) { cn = c1; hn = hp1; }
      c1 = cn; hp1 = hn;
      h1w[(bh * 32 + fb) * HH + hc0 + fc] = hn;
    }
    bar_arrive(myA, stamp);          // publish h1(t); latency hidden under U2-half

    // ---------- layer 2, U2 half: acc2 = h2r @ U2  (needs B(t-1)) ----------
    bar_wait(fB, stamp - 1u);        // covered by the whole L1 phase above
    #pragma unroll
    for (int i = 0; i < 8; ++i) acc[i] = 0.f;
    stage_ld(pre, h2r_half, tid);
    __syncthreads(); stage_st(hlds, pre, tid); __syncthreads();
    stage_ld(pre, h2r_half + 256, tid);
    inner8(acc, u2row, h4base, kq8, bg);
    __syncthreads(); stage_st(hlds, pre, tid); __syncthreads();
    inner8(acc, u2row + 256, h4base, kq8, bg);

    // ---------- layer 2, W2 half: acc2 += h1w @ W2  (needs A(t)) ----------
    bar_wait(fA, stamp);             // covered by U2-half above
    stage_ld(pre, h1w_half, tid);
    __syncthreads(); stage_st(hlds, pre, tid); __syncthreads();
    stage_ld(pre, h1w_half + 256, tid);
    inner8(acc, w2row, h4base, kq8, bg);
    __syncthreads(); stage_st(hlds, pre, tid); __syncthreads();
    inner8(acc, w2row + 256, h4base, kq8, bg);

    __syncthreads();
    #pragma unroll
    for (int i = 0; i < 8; ++i) zred[kq * 544 + (bg * 8 + i) * 17 + zcl] = acc[i];
    __syncthreads();
    if (tid < 128) {
      float z[4];
      #pragma unroll
      for (int g = 0; g < 4; ++g) {
        float s = 0.f;
        #pragma unroll
        for (int q = 0; q < 8; ++q) s += zred[q * 544 + fb * 17 + g * 4 + fc];
        z[g] = s + b2w[g * 4 + fc];
      }
      int tok = tokens[(bh * 32 + fb) * TT + t];
      float si = 1.f / (1.f + expf(-z[0]));
      float sf = 1.f / (1.f + expf(-z[1]));
      float gg = tanhf(z[2]);
      float so = 1.f / (1.f + expf(-z[3]));
      float cn = sf * c2 + si * gg;
      float hn = so * tanhf(cn);
      if (tok == 0) { cn = c2; hn = hp2; }
      c2 = cn; hp2 = hn;
      h2w[(bh * 32 + fb) * HH + hc0 + fc] = hn;
    }
    bar_arrive(myB, stamp);          // publish h2(t); waited early next step
  }

  // ---------- final dense: out = h2(t=511, in h2A) @ Wd + bd ----------
  bar_wait(fB, (unsigned)TT + 1u);   // all h2 final rows of this half visible
  if (ct < 4) {
    int idx = ct * 512 + tid;        // 0..2047 per half
    int b = idx >> 6, f = idx & 63;
    const float* hf = h2A + (bh * 32 + b) * HH;
    float a = bd[f];
    #pragma unroll 8
    for (int k = 0; k < HH; ++k) a += hf[k] * Wd[(size_t)k * FF + f];
    out[(bh * 32 + b) * FF + f] = a;
  }
}

extern "C" void kernel_launch(void* const* d_in, const int* in_sizes, int n_in,
                              void* d_out, int out_size, void* d_ws, size_t ws_size,
                              hipStream_t stream) {
  const int*   tokens = (const int*)  d_in[0];
  const float* emb    = (const float*)d_in[1];
  const float* W1     = (const float*)d_in[2];
  const float* U1     = (const float*)d_in[3];
  const float* b1     = (const float*)d_in[4];
  const float* W2     = (const float*)d_in[5];
  const float* U2     = (const float*)d_in[6];
  const float* b2     = (const float*)d_in[7];
  const float* Wd     = (const float*)d_in[8];
  const float* bd     = (const float*)d_in[9];
  float*    out   = (float*)d_out;
  unsigned* flags = (unsigned*)d_ws;
  float*    wsf   = (float*)((char*)d_ws + FLAG_WORDS * 4);

  // Host-side module attribute (graph-capture safe); needed for >64 KB LDS.
  hipFuncSetAttribute((const void*)lstm_fused3,
                      hipFuncAttributeMaxDynamicSharedMemorySize, LDS_BYTES);

  hipMemsetAsync(d_ws, 0, FLAG_WORDS * 4, stream);   // zero flag region

  void* args[] = { &tokens, &emb, &W1, &U1, &b1, &W2, &U2, &b2, &Wd, &bd,
                   &out, &wsf, &flags };
  hipLaunchCooperativeKernel((void*)lstm_fused3, dim3(NWG), dim3(NTHR),
                             args, LDS_BYTES, stream);
}